// Round 2
// baseline (292.355 us; speedup 1.0000x reference)
//
#include <hip/hip_runtime.h>
#include <math.h>

#define NL  1024     // N_LEVELS
#define KP1 9        // K+1
#define NB  4096     // direct-mapped buckets (8 KB u16 table -> 8 blocks/CU)

// d_ws float layout:
//   [0]=lo0  [1]=inv  [2..3] pad
//   [WS_PAIR .. +2064)  float2 pairs {B[i], tab[i]}, i in [0,1032): 1023 real
//                       boundaries, [1023]=INF, 8 INF overrun pads
//   [WS_BKT  .. +2048)  4096 x u16 bucket->start-count table
#define WS_PAIR 4
#define WS_BKT  (WS_PAIR + 2*(NL+8))   // float idx 2068, byte 8272 (16B aligned)

// order-preserving float<->uint map (total order incl. negatives)
__device__ __forceinline__ unsigned oi(float f) {
    unsigned u = __float_as_uint(f);
    return (u & 0x80000000u) ? ~u : (u | 0x80000000u);
}
__device__ __forceinline__ float unoi(unsigned k) {
    return __uint_as_float((k & 0x80000000u) ? (k & 0x7fffffffu) : ~k);
}

// bucket index — MUST be the identical fp32 op sequence in build and main
// kernels (monotone: fp sub/mul-by-positive/trunc/clamp are all monotone).
__device__ __forceinline__ int bidx(float x, float lo0, float inv) {
    float t = (x - lo0) * inv;
    int j = (int)t;              // trunc toward zero; clamped below anyway
    j = j < 0 ? 0 : j;
    j = j > (NB - 1) ? (NB - 1) : j;
    return j;
}

// ---------------------------------------------------------------------------
// Build kernel (1 block, 1024 threads):
//  1. tab[i]  = reference threshold-chain output for level i (exact replica)
//  2. B[i]    = smallest fp32 x where pair (i,i+1) chooses RIGHT, via bit-level
//               binary search of the exact reference predicate !(|x-l|<|x-r|)
//  3. pairs[i] = {B[i], tab[i]}   (scan's terminating read yields the answer)
//  4. bucket[j] = #{ i : bidx(B[i]) < j }   (u16, searchsorted start counts)
// ---------------------------------------------------------------------------
__global__ __launch_bounds__(1024) void build_kernel(
    const float* __restrict__ h, const float* __restrict__ d,
    const float* __restrict__ T, const float* __restrict__ bp,
    float* __restrict__ ws)
{
    __shared__ float s_g[NL];
    __shared__ float s_B[NL];     // 1023 boundaries + [1023]=INF
    __shared__ int   s_jb[NL];    // bidx of each boundary + sentinel
    __shared__ float s_lo0, s_inv;

    const int tid = threadIdx.x;
    float g = h[tid * KP1];
    s_g[tid] = g;

    // 1. out-value table (exact replica of reference fp32 sequence)
    float outv;
    {
        float v = g, o = 0.0f, b = bp[0];
#pragma unroll
        for (int t = 1; t <= 8; ++t) {
            float z = ((v - T[t]) >= 0.0f) ? 1.0f : 0.0f;
            o = o + z * d[t];
            if (t != 8) v = h[tid * KP1 + (t + 1)];
        }
        outv = o - b;
    }
    __syncthreads();

    // 2. exact fp32 decision boundary per adjacent pair
    if (tid < NL - 1) {
        float l = s_g[tid], r = s_g[tid + 1];
        unsigned a = oi(l), b2 = oi(r);   // predicate false at l, true at r
        while (a < b2) {
            unsigned m = a + ((b2 - a) >> 1);
            float xm = unoi(m);
            float dl = fabsf(xm - l), dr = fabsf(xm - r);
            if (!(dl < dr)) b2 = m; else a = m + 1;
        }
        s_B[tid] = unoi(a);
    } else {
        s_B[tid] = INFINITY;
    }
    __syncthreads();

    if (tid == 0) {
        float lo0 = s_B[0];
        float inv = (float)NB / (s_B[NL - 2] - lo0);
        s_lo0 = lo0; s_inv = inv;
        ws[0] = lo0; ws[1] = inv;
    }
    __syncthreads();

    float lo0 = s_lo0, inv = s_inv;
    s_jb[tid] = (tid < NL - 1) ? bidx(s_B[tid], lo0, inv) : 0x7fffffff;

    // 3. interleaved {boundary, value} pairs + overrun pads
    ws[WS_PAIR + 2 * tid]     = s_B[tid];
    ws[WS_PAIR + 2 * tid + 1] = outv;
    if (tid < 8) {
        ws[WS_PAIR + 2 * (NL + tid)]     = INFINITY;
        ws[WS_PAIR + 2 * (NL + tid) + 1] = 0.0f;
    }
    __syncthreads();

    // 4. bucket start counts: lower_bound over sorted s_jb
    unsigned short* bucket = (unsigned short*)(ws + WS_BKT);
    for (int j = tid; j < NB; j += 1024) {
        int lo = 0;
#pragma unroll
        for (int s = 512; s >= 1; s >>= 1)
            if (s_jb[lo + s - 1] < j) lo += s;
        bucket[j] = (unsigned short)lo;
    }
}

// ---------------------------------------------------------------------------
// Main kernel. Round-2 change: memory-level parallelism.
//  - 8 elements (2x float4) per thread per iteration
//  - next iteration's 2 loads issued BEFORE processing current (software
//    pipeline) -> up to 4 float4 loads in flight per wave (4x outstanding
//    bytes vs round-1's single load)
//  - scan chains phase-split: 8 bucket reads issue, then 8 pair reads issue,
//    then checks -> LDS waits overlap instead of serializing per element
// LDS = 8.3 KB pairs + 8 KB buckets ~= 16.5 KB -> 8 blocks/CU (32 waves).
// ---------------------------------------------------------------------------
typedef float vf4 __attribute__((ext_vector_type(4)));

__global__ __launch_bounds__(256) void ps_act_kernel(
    const float* __restrict__ x,
    const float* __restrict__ ws,
    float* __restrict__ out,
    int n4)
{
    __shared__ __align__(16) float          spair[2 * (NL + 8)];
    __shared__ __align__(16) unsigned short sbk[NB];

    const int tid = threadIdx.x;
    // vectorized staging: 516 float4s of pairs, 512 uint4s of buckets
    {
        const float4* wp4 = (const float4*)(ws + WS_PAIR);
        float4* sp4 = (float4*)spair;
        for (int i = tid; i < 2 * (NL + 8) / 4; i += 256) sp4[i] = wp4[i];
        const uint4* wb4 = (const uint4*)(ws + WS_BKT);
        uint4* sb4 = (uint4*)sbk;
        for (int i = tid; i < NB * 2 / 16; i += 256) sb4[i] = wb4[i];
    }
    const float lo0 = ws[0];
    const float inv = ws[1];
    __syncthreads();

    const float4* __restrict__ x4 = (const float4*)x;
    float4* __restrict__ o4 = (float4*)out;
    const float2* pp = (const float2*)spair;
    const int stride = gridDim.x * blockDim.x;

    int i4 = blockIdx.x * blockDim.x + tid;

    float4 va = make_float4(0.f, 0.f, 0.f, 0.f);
    float4 vb = make_float4(0.f, 0.f, 0.f, 0.f);
    if (i4 < n4)          va = x4[i4];
    if (i4 + stride < n4) vb = x4[i4 + stride];

    while (i4 < n4) {
        const int inext = i4 + 2 * stride;
        // software-pipelined prefetch of next iteration's inputs
        float4 na = make_float4(0.f, 0.f, 0.f, 0.f);
        float4 nb = make_float4(0.f, 0.f, 0.f, 0.f);
        if (inext < n4)          na = x4[inext];
        if (inext + stride < n4) nb = x4[inext + stride];

        float xf[8] = {va.x, va.y, va.z, va.w, vb.x, vb.y, vb.z, vb.w};
        int ni[8];
#pragma unroll
        for (int e = 0; e < 8; ++e)
            ni[e] = sbk[bidx(xf[e], lo0, inv)];      // 8 u16 reads in flight
        float2 pv[8];
#pragma unroll
        for (int e = 0; e < 8; ++e)
            pv[e] = pp[ni[e]];                       // 8 b64 reads in flight
        float xo[8];
#pragma unroll
        for (int e = 0; e < 8; ++e) {
            int    n_ = ni[e];
            float2 p_ = pv[e];
            // avg ~0.13 extra iterations; INF pads guarantee termination
            while (p_.x <= xf[e]) { ++n_; p_ = pp[n_]; }
            xo[e] = p_.y;
        }

        // out is write-only: nontemporal stores keep x resident in L2/L3
        vf4 o0 = {xo[0], xo[1], xo[2], xo[3]};
        __builtin_nontemporal_store(o0, (vf4*)&o4[i4]);
        if (i4 + stride < n4) {
            vf4 o1 = {xo[4], xo[5], xo[6], xo[7]};
            __builtin_nontemporal_store(o1, (vf4*)&o4[i4 + stride]);
        }

        i4 = inext;
        va = na;
        vb = nb;
    }
}

extern "C" void kernel_launch(void* const* d_in, const int* in_sizes, int n_in,
                              void* d_out, int out_size, void* d_ws, size_t ws_size,
                              hipStream_t stream) {
    const float* x = (const float*)d_in[0];
    const float* h = (const float*)d_in[1];
    const float* d = (const float*)d_in[2];
    const float* T = (const float*)d_in[3];
    const float* b = (const float*)d_in[4];
    float* out = (float*)d_out;
    float* ws  = (float*)d_ws;

    int n  = in_sizes[0];
    int n4 = n / 4;

    build_kernel<<<1, 1024, 0, stream>>>(h, d, T, b, ws);
    // 4096 blocks x 256: each thread sweeps 8 float4s in 4 pipelined
    // iterations (2 loads live + 2 prefetched = 4 in flight per wave).
    ps_act_kernel<<<4096, 256, 0, stream>>>(x, ws, out, n4);
}

// Round 3
// 251.616 us; speedup vs baseline: 1.1619x; 1.1619x over previous
//
#include <hip/hip_runtime.h>
#include <math.h>

#define NL  1024     // N_LEVELS
#define KP1 9        // K+1
#define NB  4096     // direct-mapped buckets (8 KB u16 table -> 8 blocks/CU)

// d_ws float layout:
//   [0]=lo0  [1]=inv  [2..3] pad
//   [WS_PAIR .. +2064)  float2 pairs {B[i], tab[i]}, i in [0,1032): 1023 real
//                       boundaries, [1023]=INF, 8 INF overrun pads
//   [WS_BKT  .. +2048)  4096 x u16 bucket->start-count table
#define WS_PAIR 4
#define WS_BKT  (WS_PAIR + 2*(NL+8))   // float idx 2068, byte 8272 (16B aligned)

// order-preserving float<->uint map (total order incl. negatives)
__device__ __forceinline__ unsigned oi(float f) {
    unsigned u = __float_as_uint(f);
    return (u & 0x80000000u) ? ~u : (u | 0x80000000u);
}
__device__ __forceinline__ float unoi(unsigned k) {
    return __uint_as_float((k & 0x80000000u) ? (k & 0x7fffffffu) : ~k);
}

// bucket index — MUST be the identical fp32 op sequence in build and main
// kernels (monotone: fp sub/mul-by-positive/trunc/clamp are all monotone).
__device__ __forceinline__ int bidx(float x, float lo0, float inv) {
    float t = (x - lo0) * inv;
    int j = (int)t;              // trunc toward zero; clamped below anyway
    j = j < 0 ? 0 : j;
    j = j > (NB - 1) ? (NB - 1) : j;
    return j;
}

// ---------------------------------------------------------------------------
// Build kernel (1 block, 1024 threads):
//  1. tab[i]  = reference threshold-chain output for level i (exact replica)
//  2. B[i]    = smallest fp32 x where pair (i,i+1) chooses RIGHT, via bit-level
//               binary search of the exact reference predicate !(|x-l|<|x-r|)
//  3. pairs[i] = {B[i], tab[i]}   (scan's terminating read yields the answer)
//  4. bucket[j] = #{ i : bidx(B[i]) < j }   (u16, searchsorted start counts)
// ---------------------------------------------------------------------------
__global__ __launch_bounds__(1024) void build_kernel(
    const float* __restrict__ h, const float* __restrict__ d,
    const float* __restrict__ T, const float* __restrict__ bp,
    float* __restrict__ ws)
{
    __shared__ float s_g[NL];
    __shared__ float s_B[NL];     // 1023 boundaries + [1023]=INF
    __shared__ int   s_jb[NL];    // bidx of each boundary + sentinel
    __shared__ float s_lo0, s_inv;

    const int tid = threadIdx.x;
    float g = h[tid * KP1];
    s_g[tid] = g;

    // 1. out-value table (exact replica of reference fp32 sequence)
    float outv;
    {
        float v = g, o = 0.0f, b = bp[0];
#pragma unroll
        for (int t = 1; t <= 8; ++t) {
            float z = ((v - T[t]) >= 0.0f) ? 1.0f : 0.0f;
            o = o + z * d[t];
            if (t != 8) v = h[tid * KP1 + (t + 1)];
        }
        outv = o - b;
    }
    __syncthreads();

    // 2. exact fp32 decision boundary per adjacent pair
    if (tid < NL - 1) {
        float l = s_g[tid], r = s_g[tid + 1];
        unsigned a = oi(l), b2 = oi(r);   // predicate false at l, true at r
        while (a < b2) {
            unsigned m = a + ((b2 - a) >> 1);
            float xm = unoi(m);
            float dl = fabsf(xm - l), dr = fabsf(xm - r);
            if (!(dl < dr)) b2 = m; else a = m + 1;
        }
        s_B[tid] = unoi(a);
    } else {
        s_B[tid] = INFINITY;
    }
    __syncthreads();

    if (tid == 0) {
        float lo0 = s_B[0];
        float inv = (float)NB / (s_B[NL - 2] - lo0);
        s_lo0 = lo0; s_inv = inv;
        ws[0] = lo0; ws[1] = inv;
    }
    __syncthreads();

    float lo0 = s_lo0, inv = s_inv;
    s_jb[tid] = (tid < NL - 1) ? bidx(s_B[tid], lo0, inv) : 0x7fffffff;

    // 3. interleaved {boundary, value} pairs + overrun pads
    ws[WS_PAIR + 2 * tid]     = s_B[tid];
    ws[WS_PAIR + 2 * tid + 1] = outv;
    if (tid < 8) {
        ws[WS_PAIR + 2 * (NL + tid)]     = INFINITY;
        ws[WS_PAIR + 2 * (NL + tid) + 1] = 0.0f;
    }
    __syncthreads();

    // 4. bucket start counts: lower_bound over sorted s_jb
    unsigned short* bucket = (unsigned short*)(ws + WS_BKT);
    for (int j = tid; j < NB; j += 1024) {
        int lo = 0;
#pragma unroll
        for (int s = 512; s >= 1; s >>= 1)
            if (s_jb[lo + s - 1] < j) lo += s;
        bucket[j] = (unsigned short)lo;
    }
}

// ---------------------------------------------------------------------------
// Main kernel. Round-3: round-2's 4-loads-in-flight pipeline, but ALL
// per-element state in NAMED SCALARS (round 2's 8-wide local arrays were
// allocated in scratch: WRITE_SIZE 131 MB -> 360 MB, VGPR_Count 24.
// Rule #20: runtime-shaped locals go to scratch; named vars go to VGPRs.)
// LDS = 8.3 KB pairs + 8 KB buckets ~= 16.5 KB -> 8 blocks/CU (32 waves).
// ---------------------------------------------------------------------------
typedef float vf4 __attribute__((ext_vector_type(4)));

__device__ __forceinline__ float4 proc4(float4 v,
                                        const float2* __restrict__ pp,
                                        const unsigned short* __restrict__ sbk,
                                        float lo0, float inv)
{
    // phase-split: 4 bucket reads issue, then 4 pair reads issue, then checks
    int n0 = sbk[bidx(v.x, lo0, inv)];
    int n1 = sbk[bidx(v.y, lo0, inv)];
    int n2 = sbk[bidx(v.z, lo0, inv)];
    int n3 = sbk[bidx(v.w, lo0, inv)];
    float2 p0 = pp[n0];
    float2 p1 = pp[n1];
    float2 p2 = pp[n2];
    float2 p3 = pp[n3];
    // avg ~0.13 extra iterations; INF pads guarantee termination
    while (p0.x <= v.x) { ++n0; p0 = pp[n0]; }
    while (p1.x <= v.y) { ++n1; p1 = pp[n1]; }
    while (p2.x <= v.z) { ++n2; p2 = pp[n2]; }
    while (p3.x <= v.w) { ++n3; p3 = pp[n3]; }
    return make_float4(p0.y, p1.y, p2.y, p3.y);
}

__global__ __launch_bounds__(256) void ps_act_kernel(
    const float* __restrict__ x,
    const float* __restrict__ ws,
    float* __restrict__ out,
    int n4)
{
    __shared__ __align__(16) float          spair[2 * (NL + 8)];
    __shared__ __align__(16) unsigned short sbk[NB];

    const int tid = threadIdx.x;
    // vectorized staging: 516 float4s of pairs, 512 uint4s of buckets
    {
        const float4* wp4 = (const float4*)(ws + WS_PAIR);
        float4* sp4 = (float4*)spair;
        for (int i = tid; i < 2 * (NL + 8) / 4; i += 256) sp4[i] = wp4[i];
        const uint4* wb4 = (const uint4*)(ws + WS_BKT);
        uint4* sb4 = (uint4*)sbk;
        for (int i = tid; i < NB * 2 / 16; i += 256) sb4[i] = wb4[i];
    }
    const float lo0 = ws[0];
    const float inv = ws[1];
    __syncthreads();

    const float4* __restrict__ x4 = (const float4*)x;
    float4* __restrict__ o4 = (float4*)out;
    const float2* pp = (const float2*)spair;
    const int stride = gridDim.x * blockDim.x;

    int i4 = blockIdx.x * blockDim.x + tid;

    float4 c0 = make_float4(0.f, 0.f, 0.f, 0.f);
    float4 c1 = make_float4(0.f, 0.f, 0.f, 0.f);
    if (i4 < n4)          c0 = x4[i4];
    if (i4 + stride < n4) c1 = x4[i4 + stride];

    while (i4 < n4) {
        const int inext = i4 + 2 * stride;
        // software-pipelined prefetch: up to 4 float4 loads in flight
        float4 f0 = make_float4(0.f, 0.f, 0.f, 0.f);
        float4 f1 = make_float4(0.f, 0.f, 0.f, 0.f);
        if (inext < n4)          f0 = x4[inext];
        if (inext + stride < n4) f1 = x4[inext + stride];

        float4 r0 = proc4(c0, pp, sbk, lo0, inv);
        // out is write-only: nontemporal stores keep x resident in L2/L3
        vf4 o0 = {r0.x, r0.y, r0.z, r0.w};
        __builtin_nontemporal_store(o0, (vf4*)&o4[i4]);

        if (i4 + stride < n4) {
            float4 r1 = proc4(c1, pp, sbk, lo0, inv);
            vf4 o1 = {r1.x, r1.y, r1.z, r1.w};
            __builtin_nontemporal_store(o1, (vf4*)&o4[i4 + stride]);
        }

        i4 = inext;
        c0 = f0;
        c1 = f1;
    }
}

extern "C" void kernel_launch(void* const* d_in, const int* in_sizes, int n_in,
                              void* d_out, int out_size, void* d_ws, size_t ws_size,
                              hipStream_t stream) {
    const float* x = (const float*)d_in[0];
    const float* h = (const float*)d_in[1];
    const float* d = (const float*)d_in[2];
    const float* T = (const float*)d_in[3];
    const float* b = (const float*)d_in[4];
    float* out = (float*)d_out;
    float* ws  = (float*)d_ws;

    int n  = in_sizes[0];
    int n4 = n / 4;

    build_kernel<<<1, 1024, 0, stream>>>(h, d, T, b, ws);
    // 4096 blocks x 256: each thread sweeps 8 float4s in 4 pipelined
    // iterations (2 loads live + 2 prefetched = 4 in flight per wave).
    ps_act_kernel<<<4096, 256, 0, stream>>>(x, ws, out, n4);
}

// Round 4
// 250.581 us; speedup vs baseline: 1.1667x; 1.0041x over previous
//
#include <hip/hip_runtime.h>
#include <math.h>

#define NL  1024     // N_LEVELS
#define KP1 9        // K+1
#define NB  4096     // direct-mapped buckets (8 KB u16 table -> 8 blocks/CU)

// d_ws float layout:
//   [0]=lo0  [1]=inv  [2..3] pad
//   [WS_PAIR .. +2064)  float2 pairs {B[i], tab[i]}, i in [0,1032): 1023 real
//                       boundaries, [1023]=INF, 8 INF overrun pads
//   [WS_BKT  .. +2048)  4096 x u16 bucket->start-count table
#define WS_PAIR 4
#define WS_BKT  (WS_PAIR + 2*(NL+8))   // float idx 2068, byte 8272 (16B aligned)

// order-preserving float<->uint map (total order incl. negatives)
__device__ __forceinline__ unsigned oi(float f) {
    unsigned u = __float_as_uint(f);
    return (u & 0x80000000u) ? ~u : (u | 0x80000000u);
}
__device__ __forceinline__ float unoi(unsigned k) {
    return __uint_as_float((k & 0x80000000u) ? (k & 0x7fffffffu) : ~k);
}

// bucket index — MUST be the identical fp32 op sequence in build and main
// kernels (monotone: fp sub/mul-by-positive/trunc/clamp are all monotone).
__device__ __forceinline__ int bidx(float x, float lo0, float inv) {
    float t = (x - lo0) * inv;
    int j = (int)t;              // trunc toward zero; clamped below anyway
    j = j < 0 ? 0 : j;
    j = j > (NB - 1) ? (NB - 1) : j;
    return j;
}

// ---------------------------------------------------------------------------
// Build kernel (1 block, 1024 threads):
//  1. tab[i]  = reference threshold-chain output for level i (exact replica)
//  2. B[i]    = smallest fp32 x where pair (i,i+1) chooses RIGHT, via bit-level
//               binary search of the exact reference predicate !(|x-l|<|x-r|)
//  3. pairs[i] = {B[i], tab[i]}   (select's terminating read yields the answer)
//  4. bucket[j] = #{ i : bidx(B[i]) < j }   (u16, searchsorted start counts)
// ---------------------------------------------------------------------------
__global__ __launch_bounds__(1024) void build_kernel(
    const float* __restrict__ h, const float* __restrict__ d,
    const float* __restrict__ T, const float* __restrict__ bp,
    float* __restrict__ ws)
{
    __shared__ float s_g[NL];
    __shared__ float s_B[NL];     // 1023 boundaries + [1023]=INF
    __shared__ int   s_jb[NL];    // bidx of each boundary + sentinel
    __shared__ float s_lo0, s_inv;

    const int tid = threadIdx.x;
    float g = h[tid * KP1];
    s_g[tid] = g;

    // 1. out-value table (exact replica of reference fp32 sequence)
    float outv;
    {
        float v = g, o = 0.0f, b = bp[0];
#pragma unroll
        for (int t = 1; t <= 8; ++t) {
            float z = ((v - T[t]) >= 0.0f) ? 1.0f : 0.0f;
            o = o + z * d[t];
            if (t != 8) v = h[tid * KP1 + (t + 1)];
        }
        outv = o - b;
    }
    __syncthreads();

    // 2. exact fp32 decision boundary per adjacent pair
    if (tid < NL - 1) {
        float l = s_g[tid], r = s_g[tid + 1];
        unsigned a = oi(l), b2 = oi(r);   // predicate false at l, true at r
        while (a < b2) {
            unsigned m = a + ((b2 - a) >> 1);
            float xm = unoi(m);
            float dl = fabsf(xm - l), dr = fabsf(xm - r);
            if (!(dl < dr)) b2 = m; else a = m + 1;
        }
        s_B[tid] = unoi(a);
    } else {
        s_B[tid] = INFINITY;
    }
    __syncthreads();

    if (tid == 0) {
        float lo0 = s_B[0];
        float inv = (float)NB / (s_B[NL - 2] - lo0);
        s_lo0 = lo0; s_inv = inv;
        ws[0] = lo0; ws[1] = inv;
    }
    __syncthreads();

    float lo0 = s_lo0, inv = s_inv;
    s_jb[tid] = (tid < NL - 1) ? bidx(s_B[tid], lo0, inv) : 0x7fffffff;

    // 3. interleaved {boundary, value} pairs + overrun pads
    ws[WS_PAIR + 2 * tid]     = s_B[tid];
    ws[WS_PAIR + 2 * tid + 1] = outv;
    if (tid < 8) {
        ws[WS_PAIR + 2 * (NL + tid)]     = INFINITY;
        ws[WS_PAIR + 2 * (NL + tid) + 1] = 0.0f;
    }
    __syncthreads();

    // 4. bucket start counts: lower_bound over sorted s_jb
    unsigned short* bucket = (unsigned short*)(ws + WS_BKT);
    for (int j = tid; j < NB; j += 1024) {
        int lo = 0;
#pragma unroll
        for (int s = 512; s >= 1; s >>= 1)
            if (s_jb[lo + s - 1] < j) lo += s;
        bucket[j] = (unsigned short)lo;
    }
}

// ---------------------------------------------------------------------------
// Main kernel. Round-4: BRANCH-FREE common path.
// R0-R3 all pinned at 82-86 us; the shared invariant was the divergent
// while-scan: P(any of 64 lanes needs an extra step) ~ 1, so nearly every
// scan instance ran 1-3 WAVE-level loop iterations, each a serial
// ds_read -> waitcnt(~120cy) -> cmp -> branch round-trip (~900 cy / proc4).
// Fix: boundaries are sorted, so read candidates pp[n] and pp[n+1]
// UNCONDITIONALLY (independent reads, issue together), select with one
// compare. Fallback scan from n+2 only when B[n+1] <= x (~0.9%/lane).
// LDS = 8.3 KB pairs + 8 KB buckets ~= 16.5 KB -> 8 blocks/CU (32 waves).
// ---------------------------------------------------------------------------
typedef float vf4 __attribute__((ext_vector_type(4)));

__device__ __forceinline__ float4 proc4(float4 v,
                                        const float2* __restrict__ pp,
                                        const unsigned short* __restrict__ sbk,
                                        float lo0, float inv)
{
    // phase 1: 4 bucket reads issue together
    int n0 = sbk[bidx(v.x, lo0, inv)];
    int n1 = sbk[bidx(v.y, lo0, inv)];
    int n2 = sbk[bidx(v.z, lo0, inv)];
    int n3 = sbk[bidx(v.w, lo0, inv)];
    // phase 2: 8 independent b64 candidate reads issue together
    float2 a0 = pp[n0], b0 = pp[n0 + 1];
    float2 a1 = pp[n1], b1 = pp[n1 + 1];
    float2 a2 = pp[n2], b2 = pp[n2 + 1];
    float2 a3 = pp[n3], b3 = pp[n3 + 1];
    // phase 3: branch-free select (B sorted: B[n] <= B[n+1])
    float r0 = (a0.x > v.x) ? a0.y : b0.y;
    float r1 = (a1.x > v.x) ? a1.y : b1.y;   // note: per-element x below
    r1 = (a1.x > v.y) ? a1.y : b1.y;
    float r2 = (a2.x > v.z) ? a2.y : b2.y;
    float r3 = (a3.x > v.w) ? a3.y : b3.y;
    // phase 4: rare fallback (b.x <= x means neither candidate terminates)
    bool f0 = (b0.x <= v.x), f1 = (b1.x <= v.y);
    bool f2 = (b2.x <= v.z), f3 = (b3.x <= v.w);
    if (__builtin_expect(f0 | f1 | f2 | f3, 0)) {
        if (f0) { int m = n0 + 2; float2 p = pp[m];
                  while (p.x <= v.x) { ++m; p = pp[m]; } r0 = p.y; }
        if (f1) { int m = n1 + 2; float2 p = pp[m];
                  while (p.x <= v.y) { ++m; p = pp[m]; } r1 = p.y; }
        if (f2) { int m = n2 + 2; float2 p = pp[m];
                  while (p.x <= v.z) { ++m; p = pp[m]; } r2 = p.y; }
        if (f3) { int m = n3 + 2; float2 p = pp[m];
                  while (p.x <= v.w) { ++m; p = pp[m]; } r3 = p.y; }
    }
    return make_float4(r0, r1, r2, r3);
}

__global__ __launch_bounds__(256) void ps_act_kernel(
    const float* __restrict__ x,
    const float* __restrict__ ws,
    float* __restrict__ out,
    int n4)
{
    __shared__ __align__(16) float          spair[2 * (NL + 8)];
    __shared__ __align__(16) unsigned short sbk[NB];

    const int tid = threadIdx.x;
    // vectorized staging: 516 float4s of pairs, 512 uint4s of buckets
    {
        const float4* wp4 = (const float4*)(ws + WS_PAIR);
        float4* sp4 = (float4*)spair;
        for (int i = tid; i < 2 * (NL + 8) / 4; i += 256) sp4[i] = wp4[i];
        const uint4* wb4 = (const uint4*)(ws + WS_BKT);
        uint4* sb4 = (uint4*)sbk;
        for (int i = tid; i < NB * 2 / 16; i += 256) sb4[i] = wb4[i];
    }
    const float lo0 = ws[0];
    const float inv = ws[1];
    __syncthreads();

    const float4* __restrict__ x4 = (const float4*)x;
    float4* __restrict__ o4 = (float4*)out;
    const float2* pp = (const float2*)spair;
    const int stride = gridDim.x * blockDim.x;

    for (int i4 = blockIdx.x * blockDim.x + tid; i4 < n4; i4 += 2 * stride) {
        const int j4 = i4 + stride;
        // two independent float4 loads issue back-to-back (2 in flight)
        float4 c0 = x4[i4];
        float4 c1 = make_float4(0.f, 0.f, 0.f, 0.f);
        if (j4 < n4) c1 = x4[j4];

        float4 r0 = proc4(c0, pp, sbk, lo0, inv);
        // out is write-only: nontemporal stores keep x resident in L2/L3
        vf4 o0 = {r0.x, r0.y, r0.z, r0.w};
        __builtin_nontemporal_store(o0, (vf4*)&o4[i4]);

        if (j4 < n4) {
            float4 r1 = proc4(c1, pp, sbk, lo0, inv);
            vf4 o1 = {r1.x, r1.y, r1.z, r1.w};
            __builtin_nontemporal_store(o1, (vf4*)&o4[j4]);
        }
    }
}

extern "C" void kernel_launch(void* const* d_in, const int* in_sizes, int n_in,
                              void* d_out, int out_size, void* d_ws, size_t ws_size,
                              hipStream_t stream) {
    const float* x = (const float*)d_in[0];
    const float* h = (const float*)d_in[1];
    const float* d = (const float*)d_in[2];
    const float* T = (const float*)d_in[3];
    const float* b = (const float*)d_in[4];
    float* out = (float*)d_out;
    float* ws  = (float*)d_ws;

    int n  = in_sizes[0];
    int n4 = n / 4;

    build_kernel<<<1, 1024, 0, stream>>>(h, d, T, b, ws);
    // 4096 blocks x 256: each thread sweeps 8 float4s, 2 per iteration.
    ps_act_kernel<<<4096, 256, 0, stream>>>(x, ws, out, n4);
}